// Round 12
// baseline (205.156 us; speedup 1.0000x reference)
//
#include <hip/hip_runtime.h>

#define DIM    1024
#define BATCH  8
#define QLEN   4096
#define SEQ    128
#define NBLK   512

typedef float vfloat4 __attribute__((ext_vector_type(4)));

__device__ __forceinline__ void grid_barrier(unsigned* cnt, int tid) {
    __threadfence();                       // each thread's writes device-visible
    __syncthreads();
    if (tid == 0) {
        __hip_atomic_fetch_add(cnt, 1u, __ATOMIC_RELAXED, __HIP_MEMORY_SCOPE_AGENT);
        while (__hip_atomic_load(cnt, __ATOMIC_ACQUIRE, __HIP_MEMORY_SCOPE_AGENT) < NBLK) {
            __builtin_amdgcn_s_sleep(2);
        }
        __threadfence();
    }
    __syncthreads();
}

// One persistent kernel, 512 blocks x 256 threads (>=2 blocks/CU co-resident).
// A: vp[es][m,b,d] partials of v (weights read once, batches in registers)
// B: yp[cd][m,b,e] partials of y (weights read once)
// C: reduce yp row + bias, stream 64 q-rows per block.
__global__ void __launch_bounds__(256)
mega(const float* __restrict__ hidden,
     const float* __restrict__ c_attn_w,
     const float* __restrict__ c_attn_b,
     const float* __restrict__ c_proj_w,
     const float* __restrict__ c_proj_b,
     float* __restrict__ vp,
     float* __restrict__ yp,
     unsigned* __restrict__ cnt,
     float* __restrict__ out) {
    __shared__ float h_s[BATCH][64];
    __shared__ float v_s[BATCH][64];
    __shared__ vfloat4 red[16][16][9];     // 36.9 KB, reused by A and B

    const int tid = threadIdx.x;
    const int bid = blockIdx.x;

    // ---------------- Phase A (R6 kernelA body) ----------------
    {
        const int es = bid & 15;
        const int c  = (bid >> 4) & 15;
        const int m  = bid >> 8;

        if (tid < 128) {                   // stage h_last[b, es*64 .. +64)
            int b = tid >> 4, e4 = tid & 15;
            const vfloat4* src = reinterpret_cast<const vfloat4*>(
                hidden + (size_t)b * (SEQ * DIM) + (size_t)(SEQ - 1) * DIM + es * 64);
            reinterpret_cast<vfloat4*>(h_s[b])[e4] = src[e4];
        }
        __syncthreads();

        const int d4 = tid & 15;
        const int eg = tid >> 4;
        const float* wbase = c_attn_w + (size_t)m * DIM * (2 * DIM) + DIM + c * 64 + d4 * 4;

        vfloat4 acc[BATCH];
#pragma unroll
        for (int b = 0; b < BATCH; ++b) acc[b] = (vfloat4){0.f, 0.f, 0.f, 0.f};
#pragma unroll
        for (int k = 0; k < 4; ++k) {
            int el = eg * 4 + k;
            int e  = es * 64 + el;
            vfloat4 w4 = *reinterpret_cast<const vfloat4*>(wbase + (size_t)e * (2 * DIM));
#pragma unroll
            for (int b = 0; b < BATCH; ++b) acc[b] += h_s[b][el] * w4;
        }
#pragma unroll
        for (int b = 0; b < BATCH; ++b) red[eg][d4][b] = acc[b];
        __syncthreads();

        if (tid < 128) {
            int b = tid >> 4, dq = tid & 15;
            vfloat4 s = red[0][dq][b];
#pragma unroll
            for (int g = 1; g < 16; ++g) s += red[g][dq][b];
            reinterpret_cast<vfloat4*>(vp)[es * 4096 + (m * BATCH + b) * 256 + c * 16 + dq] = s;
        }
    }

    grid_barrier(&cnt[0], tid);

    // ---------------- Phase B (R6 kernelB body -> yp) ----------------
    {
        const int ce = bid & 15;
        const int cd = (bid >> 4) & 15;
        const int m  = bid >> 8;

        if (tid < 128) {                   // v_s[b][dl] for this d-chunk
            int b = tid >> 4, d4 = tid & 15;
            vfloat4 s = reinterpret_cast<const vfloat4*>(
                c_attn_b + (size_t)m * 2 * DIM + DIM)[cd * 16 + d4];
            const vfloat4* vp4 = reinterpret_cast<const vfloat4*>(vp);
#pragma unroll
            for (int es = 0; es < 16; ++es) {
                s += vp4[es * 4096 + (m * BATCH + b) * 256 + cd * 16 + d4];
            }
            reinterpret_cast<vfloat4*>(v_s[b])[d4] = s;
        }
        __syncthreads();

        const int e4 = tid & 15;
        const int dg = tid >> 4;
        const float* wbase = c_proj_w + (size_t)m * DIM * DIM + ce * 64 + e4 * 4;

        vfloat4 acc[BATCH];
#pragma unroll
        for (int b = 0; b < BATCH; ++b) acc[b] = (vfloat4){0.f, 0.f, 0.f, 0.f};
#pragma unroll
        for (int j = 0; j < 4; ++j) {
            int dl = dg * 4 + j;
            int d  = cd * 64 + dl;
            vfloat4 w4 = *reinterpret_cast<const vfloat4*>(wbase + (size_t)d * DIM);
#pragma unroll
            for (int b = 0; b < BATCH; ++b) acc[b] += v_s[b][dl] * w4;
        }
#pragma unroll
        for (int b = 0; b < BATCH; ++b) red[dg][e4][b] = acc[b];
        __syncthreads();

        if (tid < 128) {
            int b = tid >> 4, eq = tid & 15;
            vfloat4 s = red[0][eq][b];
#pragma unroll
            for (int g = 1; g < 16; ++g) s += red[g][eq][b];
            reinterpret_cast<vfloat4*>(yp)[cd * 4096 + (m * BATCH + b) * 256 + ce * 16 + eq] = s;
        }
    }

    grid_barrier(&cnt[1], tid);

    // ---------------- Phase C: reduce + broadcast (64 q-rows/block) ----------
    {
        const int b  = bid >> 6;           // 8
        const int q0 = (bid & 63) * 64;    // 64 chunks of 64 rows
        const int t  = tid;                // e4 slot

        const vfloat4* bias4 = reinterpret_cast<const vfloat4*>(c_proj_b);
        const vfloat4* yp4 = reinterpret_cast<const vfloat4*>(yp);
        vfloat4 val = bias4[t];
#pragma unroll
        for (int cd = 0; cd < 16; ++cd) {
            val += yp4[cd * 4096 + b * 256 + t];
        }
        if (b == 0) {
            val += bias4[256 + t];
#pragma unroll
            for (int cd = 0; cd < 16; ++cd) {
                val += yp4[cd * 4096 + BATCH * 256 + t];
            }
        }

        vfloat4* o = reinterpret_cast<vfloat4*>(out) + ((size_t)b * QLEN + q0) * 256 + t;
#pragma unroll 8
        for (int q = 0; q < 64; ++q) {
            __builtin_nontemporal_store(val, o + (size_t)q * 256);
        }
    }
}

extern "C" void kernel_launch(void* const* d_in, const int* in_sizes, int n_in,
                              void* d_out, int out_size, void* d_ws, size_t ws_size,
                              hipStream_t stream) {
    // inputs: encoder_hidden_states, hidden_states, q_w, q_b,
    //         c_attn_w, c_attn_b, c_proj_w, c_proj_b
    const float* hidden   = (const float*)d_in[1];
    const float* c_attn_w = (const float*)d_in[4];
    const float* c_attn_b = (const float*)d_in[5];
    const float* c_proj_w = (const float*)d_in[6];
    const float* c_proj_b = (const float*)d_in[7];
    float* out = (float*)d_out;

    float* vp = (float*)d_ws;                          // 1 MB
    float* yp = vp + 16 * 16384;                       // 1 MB
    unsigned* cnt = (unsigned*)((char*)d_ws + (2u << 20));

    hipMemsetAsync(cnt, 0, 64, stream);                // zero barrier counters
    mega<<<NBLK, 256, 0, stream>>>(hidden, c_attn_w, c_attn_b, c_proj_w,
                                   c_proj_b, vp, yp, cnt, out);
}

// Round 13
// 38.979 us; speedup vs baseline: 5.2632x; 5.2632x over previous
//
#include <hip/hip_runtime.h>

#define DIM    1024
#define BATCH  8
#define QLEN   4096
#define SEQ    128

typedef float vfloat4 __attribute__((ext_vector_type(4)));

// ---------- K1: fused v + yp ----------
// 256 blocks: m = bid&1, cd = (bid>>1)&15, ceg = bid>>5 (8 e-ranges of 128).
// Blocks sharing (m,cd) have bids differing by 32 -> same bid%8 -> same XCD,
// so the 8x re-read of the 256KB Wv panel is L2-served.
// Phase 1: v_s[b][dl] = c_attn_b[m,DIM+d] + sum_{e=0..1023} h_last[b,e]*Wv[m,e,DIM+d]
// Phase 2: yp[cd][m,b, ceg-range] = sum_{d in cd-chunk} v_s[b][dl]*Wp[m,d,e]
__global__ void __launch_bounds__(256) fused_AB(const float* __restrict__ hidden,
                                                const float* __restrict__ c_attn_w,
                                                const float* __restrict__ c_attn_b,
                                                const float* __restrict__ c_proj_w,
                                                float* __restrict__ yp) {
    __shared__ float h_ch[BATCH][256];      // 8 KB, h_last e-chunk
    __shared__ vfloat4 red[16 * 16 * 9];    // 36.9 KB, reused by both phases
    __shared__ float v_s[BATCH][64];        // 2 KB

    const int tid = threadIdx.x;
    const int m   = blockIdx.x & 1;
    const int cd  = (blockIdx.x >> 1) & 15;
    const int ceg = blockIdx.x >> 5;

    // ---- Phase 1 (R8-proven body): full-e reduction for this (m, cd) ----
    const int d4 = tid & 15;                // float4 of d within 64-chunk
    const int eg = tid >> 4;                // 16 e-groups
    const float* wv = c_attn_w + (size_t)m * DIM * (2 * DIM) + DIM + cd * 64 + d4 * 4;

    vfloat4 acc[BATCH];
#pragma unroll
    for (int b = 0; b < BATCH; ++b) acc[b] = (vfloat4){0.f, 0.f, 0.f, 0.f};

    for (int ch = 0; ch < 4; ++ch) {
        // stage h_last[:, ch*256 .. +256): 512 float4 by 256 threads
#pragma unroll
        for (int k = 0; k < 2; ++k) {
            int idx = tid + 256 * k;        // 0..511
            int hb = idx >> 6;
            int c4 = idx & 63;
            reinterpret_cast<vfloat4*>(h_ch[hb])[c4] =
                reinterpret_cast<const vfloat4*>(
                    hidden + (size_t)hb * (SEQ * DIM) + (size_t)(SEQ - 1) * DIM
                    + ch * 256)[c4];
        }
        __syncthreads();
#pragma unroll
        for (int j = 0; j < 16; ++j) {
            int el = eg * 16 + j;           // 0..255
            int e  = ch * 256 + el;
            vfloat4 w4 = *reinterpret_cast<const vfloat4*>(wv + (size_t)e * (2 * DIM));
#pragma unroll
            for (int b = 0; b < BATCH; ++b) acc[b] += h_ch[b][el] * w4;
        }
        __syncthreads();                    // before next h_ch overwrite
    }

#pragma unroll
    for (int b = 0; b < BATCH; ++b) red[(eg * 16 + d4) * 9 + b] = acc[b];
    __syncthreads();

    if (tid < 128) {                        // reduce 16 e-groups + bias -> v_s
        int b = tid >> 4, dq = tid & 15;
        vfloat4 s = red[dq * 9 + b];
#pragma unroll
        for (int g = 1; g < 16; ++g) s += red[(g * 16 + dq) * 9 + b];
        vfloat4 bias = *reinterpret_cast<const vfloat4*>(
            c_attn_b + (size_t)m * 2 * DIM + DIM + cd * 64 + dq * 4);
        reinterpret_cast<vfloat4*>(v_s[b])[dq] = s + bias;
    }
    __syncthreads();

    // ---- Phase 2: yp partial over 64d x 128e tile ----
    const int e4 = tid & 31;                // float4 of e within 128-e range
    const int dg = tid >> 5;                // 8 d-groups of 8
    const float* wp = c_proj_w + (size_t)m * DIM * DIM + ceg * 128 + e4 * 4;

    vfloat4 acc2[BATCH];
#pragma unroll
    for (int b = 0; b < BATCH; ++b) acc2[b] = (vfloat4){0.f, 0.f, 0.f, 0.f};

#pragma unroll
    for (int j = 0; j < 8; ++j) {
        int dl = dg * 8 + j;                // 0..63
        int d  = cd * 64 + dl;
        vfloat4 w4 = *reinterpret_cast<const vfloat4*>(wp + (size_t)d * DIM);
#pragma unroll
        for (int b = 0; b < BATCH; ++b) acc2[b] += v_s[b][dl] * w4;
    }
#pragma unroll
    for (int b = 0; b < BATCH; ++b) red[(dg * 32 + e4) * 9 + b] = acc2[b];
    __syncthreads();

    {                                       // reduce 8 d-groups -> yp (all 256 thr)
        int b = tid >> 5, eq = tid & 31;
        vfloat4 s = red[eq * 9 + b];
#pragma unroll
        for (int g = 1; g < 8; ++g) s += red[(g * 32 + eq) * 9 + b];
        reinterpret_cast<vfloat4*>(yp)[cd * 4096 + (m * BATCH + b) * 256 + ceg * 32 + eq] = s;
    }
}

// ---------- Kernel C (R6-proven): reduce yp + bias, broadcast store ----------
// 2048 blocks: b = bid>>8, q0 = (bid&255)*16; 16 contiguous q-rows per block.
__global__ void __launch_bounds__(256) bcast_reduce(const float* __restrict__ yp,
                                                    const float* __restrict__ c_proj_b,
                                                    float* __restrict__ out) {
    int b = blockIdx.x >> 8;
    int q0 = (blockIdx.x & 255) * 16;
    int t = threadIdx.x;                    // e4 = t (256 float4 = 1024 e)

    const vfloat4* bias4 = reinterpret_cast<const vfloat4*>(c_proj_b);
    const vfloat4* yp4 = reinterpret_cast<const vfloat4*>(yp);
    vfloat4 val = bias4[t];
#pragma unroll
    for (int cd = 0; cd < 16; ++cd) {
        val += yp4[cd * 4096 + b * 256 + t];
    }
    if (b == 0) {
        val += bias4[256 + t];
#pragma unroll
        for (int cd = 0; cd < 16; ++cd) {
            val += yp4[cd * 4096 + BATCH * 256 + t];
        }
    }

    vfloat4* o = reinterpret_cast<vfloat4*>(out) + ((size_t)b * QLEN + q0) * 256 + t;
#pragma unroll
    for (int q = 0; q < 16; ++q) {
        __builtin_nontemporal_store(val, o + (size_t)q * 256);
    }
}

extern "C" void kernel_launch(void* const* d_in, const int* in_sizes, int n_in,
                              void* d_out, int out_size, void* d_ws, size_t ws_size,
                              hipStream_t stream) {
    // inputs: encoder_hidden_states, hidden_states, q_w, q_b,
    //         c_attn_w, c_attn_b, c_proj_w, c_proj_b
    const float* hidden   = (const float*)d_in[1];
    const float* c_attn_w = (const float*)d_in[4];
    const float* c_attn_b = (const float*)d_in[5];
    const float* c_proj_w = (const float*)d_in[6];
    const float* c_proj_b = (const float*)d_in[7];
    float* out = (float*)d_out;

    float* yp = (float*)d_ws;               // 16*16384 f32 = 1 MB

    fused_AB<<<256, 256, 0, stream>>>(hidden, c_attn_w, c_attn_b, c_proj_w, yp);
    bcast_reduce<<<2048, 256, 0, stream>>>(yp, c_proj_b, out);
}